// Round 2
// baseline (481.068 us; speedup 1.0000x reference)
//
#include <hip/hip_runtime.h>
#include <hip/hip_bf16.h>
#include <cstdint>

#define NB 4
#define NS 2048
#define ND 1024
#define NH 16
#define NDH 64
#define NM (NB*NS)       // 8192
#define N3D (3*ND)       // 3072

typedef __attribute__((ext_vector_type(8))) short short8;
typedef __attribute__((ext_vector_type(4))) float f32x4;

__device__ __forceinline__ float bf2f(unsigned short u) {
  unsigned int i = ((unsigned int)u) << 16;
  return __builtin_bit_cast(float, i);
}
__device__ __forceinline__ unsigned short f2bf(float f) {
  unsigned int i = __builtin_bit_cast(unsigned int, f);
  i = (i + 0x7FFFu + ((i >> 16) & 1u)) >> 16;
  return (unsigned short)i;
}

#define GLD16(g, l) __builtin_amdgcn_global_load_lds( \
    (__attribute__((address_space(1))) void*)(void*)(g), \
    (__attribute__((address_space(3))) void*)(l), 16, 0, 0)

// ------------------------------------------------------------ f32 -> bf16 cast
__global__ __launch_bounds__(256) void cvt_bf16_k(
    const float* __restrict__ in, unsigned short* __restrict__ out, int n)
{
  const int i = (blockIdx.x * 256 + threadIdx.x) * 4;
  if (i + 3 < n) {
    const f32x4 v = *(const f32x4*)(in + i);
    unsigned short o0 = f2bf(v[0]), o1 = f2bf(v[1]), o2 = f2bf(v[2]), o3 = f2bf(v[3]);
    typedef __attribute__((ext_vector_type(4))) unsigned short us4;
    us4 o = {o0, o1, o2, o3};
    *(us4*)(out + i) = o;
  }
}

// --------------------------------------------- f32 [rows][cols] -> bf16 [cols][rows]
__global__ __launch_bounds__(256) void transpose_cvt_k(
    const float* __restrict__ in, unsigned short* __restrict__ out,
    int rows, int cols)
{
  __shared__ unsigned short tile[32][33];
  const int c0 = blockIdx.x * 32, r0 = blockIdx.y * 32;
  const int tx = threadIdx.x & 31, ty = threadIdx.x >> 5;   // ty 0..7
  #pragma unroll
  for (int i = ty; i < 32; i += 8)
    tile[i][tx] = f2bf(in[(size_t)(r0 + i) * cols + (c0 + tx)]);
  __syncthreads();
  #pragma unroll
  for (int i = ty; i < 32; i += 8)
    out[(size_t)(c0 + i) * rows + (r0 + tx)] = tile[tx][i];
}

// ------------------------------------------------- GEMM  C = A * Bt^T + bias
// A[M][K] bf16 row-major, Bt[N][K] bf16 row-major, f32 bias. 128x128 tile,
// BK=32, 4 waves (2x2 of 64x64), global_load_lds staging (m97 structure).
template<bool OUT_F32>
__global__ __launch_bounds__(256) void gemm_bt_bias(
    const unsigned short* __restrict__ A,
    const unsigned short* __restrict__ Bt,
    const float* __restrict__ bias,
    unsigned short* __restrict__ Cb,
    float* __restrict__ Cf,
    int M, int N, int K)
{
  __shared__ __align__(16) unsigned short Alds[128 * 32];
  __shared__ __align__(16) unsigned short Blds[128 * 32];
  const int nbn = N >> 7;
  const int bm = blockIdx.x / nbn, bn = blockIdx.x % nbn;
  const int m0 = bm << 7, n0 = bn << 7;
  const int w = threadIdx.x >> 6, l = threadIdx.x & 63;
  const int wr = w >> 1, wc = w & 1;
  const int lr = l & 15, lg = l >> 4;

  // staging: wave w covers rows w*32 .. w*32+31 of each 128x32 tile,
  // two global_load_lds of 16 rows each; lane l -> row l/4, 16B chunk l%4
  const unsigned short* gA = A + (size_t)(m0 + w * 32 + (l >> 2)) * K + (l & 3) * 8;
  const unsigned short* gB = Bt + (size_t)(n0 + w * 32 + (l >> 2)) * K + (l & 3) * 8;
  unsigned short* lA = Alds + (w * 32) * 32;   // wave-uniform LDS base
  unsigned short* lB = Blds + (w * 32) * 32;

  f32x4 acc[4][4] = {};

  for (int k0 = 0; k0 < K; k0 += 32) {
    GLD16(gA + k0, lA);
    GLD16(gA + k0 + (size_t)16 * K, lA + 16 * 32);
    GLD16(gB + k0, lB);
    GLD16(gB + k0 + (size_t)16 * K, lB + 16 * 32);
    __syncthreads();

    short8 a[4], b[4];
    #pragma unroll
    for (int i = 0; i < 4; ++i)
      a[i] = *(const short8*)(Alds + (wr * 64 + i * 16 + lr) * 32 + lg * 8);
    #pragma unroll
    for (int j = 0; j < 4; ++j)
      b[j] = *(const short8*)(Blds + (wc * 64 + j * 16 + lr) * 32 + lg * 8);

    #pragma unroll
    for (int i = 0; i < 4; ++i)
      #pragma unroll
      for (int j = 0; j < 4; ++j)
        acc[i][j] = __builtin_amdgcn_mfma_f32_16x16x32_bf16(a[i], b[j], acc[i][j], 0, 0, 0);
    __syncthreads();
  }

  #pragma unroll
  for (int j = 0; j < 4; ++j) {
    const int col = n0 + wc * 64 + j * 16 + lr;
    const float bv = bias[col];
    #pragma unroll
    for (int i = 0; i < 4; ++i) {
      #pragma unroll
      for (int r = 0; r < 4; ++r) {
        const int row = m0 + wr * 64 + i * 16 + lg * 4 + r;
        const float v = acc[i][j][r] + bv;
        if (OUT_F32) Cf[(size_t)row * N + col] = v;
        else         Cb[(size_t)row * N + col] = f2bf(v);
      }
    }
  }
}

// ----------------------------------------------------- causal flash attention
// qkv[B*S][3D] bf16; per wave: 16 q-rows of one (b,h); 32-key tiles.
__global__ __launch_bounds__(256) void attn_fwd(
    const unsigned short* __restrict__ qkv,
    unsigned short* __restrict__ out)
{
  __shared__ __align__(16) unsigned short Plds[4][16 * 32];  // per-wave P tile
  const int blk = blockIdx.x;
  const int bh = blk >> 5;               // 64 (b,h) pairs
  const int qt = blk & 31;               // 32 q-tiles of 64 rows
  const int b = bh >> 4, h = bh & 15;
  const int w = threadIdx.x >> 6, l = threadIdx.x & 63;
  const int lr = l & 15, lg = l >> 4;
  const int q0 = qt * 64 + w * 16;

  const size_t rs = N3D;
  const unsigned short* base = qkv + (size_t)b * NS * rs + (size_t)h * NDH;
  const unsigned short* Kb = base + ND;
  const unsigned short* Vb = base + 2 * ND;

  // Q fragments (A-operand): lane holds Q[q0+lr][lg*8 + j (+32)]
  short8 qf0, qf1;
  {
    const unsigned short* qrow = base + (size_t)(q0 + lr) * rs + lg * 8;
    qf0 = *(const short8*)(qrow);
    qf1 = *(const short8*)(qrow + 32);
  }

  float m_run[4], l_run[4];
  f32x4 o[4];
  f32x4 zero = {0.f, 0.f, 0.f, 0.f};
  #pragma unroll
  for (int r = 0; r < 4; ++r) { m_run[r] = -__builtin_inff(); l_run[r] = 0.f; }
  #pragma unroll
  for (int nb = 0; nb < 4; ++nb) o[nb] = zero;

  const int ktmax = (q0 + 15) >> 5;
  for (int kt = 0; kt <= ktmax; ++kt) {
    const int kbase = kt << 5;
    // K^T fragments (B-operand): lane holds K[kbase+block+lr][lg*8 + j]
    const unsigned short* krow = Kb + (size_t)(kbase + lr) * rs + lg * 8;
    short8 k00 = *(const short8*)(krow);
    short8 k01 = *(const short8*)(krow + 32);
    short8 k10 = *(const short8*)(krow + 16 * rs);
    short8 k11 = *(const short8*)(krow + 16 * rs + 32);

    f32x4 s0 = zero, s1 = zero;
    s0 = __builtin_amdgcn_mfma_f32_16x16x32_bf16(qf0, k00, s0, 0, 0, 0);
    s0 = __builtin_amdgcn_mfma_f32_16x16x32_bf16(qf1, k01, s0, 0, 0, 0);
    s1 = __builtin_amdgcn_mfma_f32_16x16x32_bf16(qf0, k10, s1, 0, 0, 0);
    s1 = __builtin_amdgcn_mfma_f32_16x16x32_bf16(qf1, k11, s1, 0, 0, 0);

    // mask -> scale -> online softmax.  D-layout: row=lg*4+r, col=lr (+16)
    float p0[4], p1[4], sf[4];
    #pragma unroll
    for (int r = 0; r < 4; ++r) {
      const int qi = q0 + lg * 4 + r;
      float t0 = (kbase + lr) <= qi ? s0[r] * 0.125f : -__builtin_inff();
      float t1 = (kbase + 16 + lr) <= qi ? s1[r] * 0.125f : -__builtin_inff();
      float mx = fmaxf(t0, t1);
      #pragma unroll
      for (int d = 1; d < 16; d <<= 1) mx = fmaxf(mx, __shfl_xor(mx, d));
      const float mnew = fmaxf(m_run[r], mx);
      sf[r] = __expf(m_run[r] - mnew);
      m_run[r] = mnew;
      p0[r] = __expf(t0 - mnew);
      p1[r] = __expf(t1 - mnew);
      float rsum = p0[r] + p1[r];
      #pragma unroll
      for (int d = 1; d < 16; d <<= 1) rsum += __shfl_xor(rsum, d);
      l_run[r] = l_run[r] * sf[r] + rsum;
    }
    #pragma unroll
    for (int nb = 0; nb < 4; ++nb)
      #pragma unroll
      for (int r = 0; r < 4; ++r) o[nb][r] *= sf[r];

    // transpose P (D-layout) -> A-frag layout through per-wave LDS
    unsigned short* pl = &Plds[w][0];
    #pragma unroll
    for (int r = 0; r < 4; ++r) {
      pl[(lg * 4 + r) * 32 + lr]      = f2bf(p0[r]);
      pl[(lg * 4 + r) * 32 + 16 + lr] = f2bf(p1[r]);
    }
    asm volatile("s_waitcnt lgkmcnt(0)" ::: "memory");   // same-wave, no barrier
    short8 pf = *(const short8*)(pl + lr * 32 + lg * 8);

    // V fragments (B-operand): lane holds V[kbase + lg*8 + j][nb*16 + lr]
    short8 vf[4];
    #pragma unroll
    for (int j = 0; j < 8; ++j) {
      const unsigned short* vrow = Vb + (size_t)(kbase + lg * 8 + j) * rs + lr;
      vf[0][j] = (short)vrow[0];
      vf[1][j] = (short)vrow[16];
      vf[2][j] = (short)vrow[32];
      vf[3][j] = (short)vrow[48];
    }
    #pragma unroll
    for (int nb = 0; nb < 4; ++nb)
      o[nb] = __builtin_amdgcn_mfma_f32_16x16x32_bf16(pf, vf[nb], o[nb], 0, 0, 0);
  }

  #pragma unroll
  for (int r = 0; r < 4; ++r) {
    const int qi = q0 + lg * 4 + r;
    const float inv = 1.0f / l_run[r];
    #pragma unroll
    for (int nb = 0; nb < 4; ++nb)
      out[(size_t)(b * NS + qi) * ND + h * NDH + nb * 16 + lr] = f2bf(o[nb][r] * inv);
  }
}

// --------------------------------------------------------------------- launch
extern "C" void kernel_launch(void* const* d_in, const int* in_sizes, int n_in,
                              void* d_out, int out_size, void* d_ws, size_t ws_size,
                              hipStream_t stream) {
  const float* x     = (const float*)d_in[0];
  const float* w_in  = (const float*)d_in[1];
  const float* b_in  = (const float*)d_in[2];
  const float* w_out = (const float*)d_in[3];
  const float* b_out = (const float*)d_in[4];
  float* out = (float*)d_out;

  char* ws = (char*)d_ws;
  size_t off = 0;
  unsigned short* x_bf    = (unsigned short*)(ws + off); off += (size_t)NM * ND * 2;    // 16 MiB
  unsigned short* qkv     = (unsigned short*)(ws + off); off += (size_t)NM * N3D * 2;   // 48 MiB
  unsigned short* attn    = (unsigned short*)(ws + off); off += (size_t)NM * ND * 2;    // 16 MiB
  unsigned short* w_in_t  = (unsigned short*)(ws + off); off += (size_t)N3D * ND * 2;   //  6 MiB
  unsigned short* w_out_t = (unsigned short*)(ws + off); off += (size_t)ND * ND * 2;    //  2 MiB

  // x -> bf16
  cvt_bf16_k<<<dim3((NM * ND) / (256 * 4)), 256, 0, stream>>>(x, x_bf, NM * ND);
  // weight transposes + cast: w[K][N] f32 -> wt[N][K] bf16
  transpose_cvt_k<<<dim3(N3D / 32, ND / 32), 256, 0, stream>>>(w_in, w_in_t, ND, N3D);
  transpose_cvt_k<<<dim3(ND / 32, ND / 32), 256, 0, stream>>>(w_out, w_out_t, ND, ND);

  // qkv = x @ w_in + b_in            (bf16 out)
  gemm_bt_bias<false><<<dim3((NM / 128) * (N3D / 128)), 256, 0, stream>>>(
      x_bf, w_in_t, b_in, qkv, nullptr, NM, N3D, ND);

  // attention
  attn_fwd<<<dim3((NB * NH) * (NS / 64)), 256, 0, stream>>>(qkv, attn);

  // out = attn @ w_out + b_out       (f32 out)
  gemm_bt_bias<true><<<dim3((NM / 128) * (ND / 128)), 256, 0, stream>>>(
      attn, w_out_t, b_out, nullptr, out, NM, ND, ND);
}